// Round 6
// baseline (1627.158 us; speedup 1.0000x reference)
//
#include <hip/hip_runtime.h>

#define NB 256
#define NT 1000
#define ND 64
#define NH 128
#define BN 16            // batch rows per block
#define NBLK (NB / BN)   // 16 blocks
#define NTHR 512         // 8 waves

typedef _Float16 f16x8 __attribute__((ext_vector_type(8)));
typedef float    f32x4 __attribute__((ext_vector_type(4)));
typedef uint     u32x4 __attribute__((ext_vector_type(4)));

__device__ __forceinline__ uint pk(float a, float b) {
    return __builtin_bit_cast(uint, __builtin_amdgcn_cvt_pkrtz(a, b));
}
__device__ __forceinline__ f16x8 packx(float4 a, float4 b) {
    u32x4 u = { pk(a.x, a.y), pk(a.z, a.w), pk(b.x, b.y), pk(b.z, b.w) };
    return __builtin_bit_cast(f16x8, u);
}
// load 8 consecutive f32, pack to one A/B fragment (8 f16)
__device__ __forceinline__ f16x8 ldWfrag(const float* p) {
    return packx(*(const float4*)p, *(const float4*)(p + 4));
}
__device__ __forceinline__ float sigmoid_f(float x) {
    float e = __builtin_amdgcn_exp2f(-1.4426950408889634f * x);
    return __builtin_amdgcn_rcpf(1.0f + e);
}
__device__ __forceinline__ float tanh_f(float x) {
    float e = __builtin_amdgcn_exp2f(-2.8853900817779268f * x);
    return 2.0f * __builtin_amdgcn_rcpf(1.0f + e) - 1.0f;
}

#define MFMA(a, b, c) __builtin_amdgcn_mfma_f32_16x16x32_f16((a), (b), (c), 0, 0, 0)

__global__
__attribute__((amdgpu_flat_work_group_size(NTHR, NTHR)))
__attribute__((amdgpu_waves_per_eu(2, 2)))
void gruode_fused(
    const float* __restrict__ x,      // (B,T,D)
    const float* __restrict__ tps,    // (T)
    const int*   __restrict__ mask,   // (B,T)
    const float* __restrict__ W_ih,   // (384,64)
    const float* __restrict__ W_hh,   // (384,128)
    const float* __restrict__ b_ih,   // (384)
    const float* __restrict__ b_hh,   // (384)
    const float* __restrict__ nW1,    // (128,128)
    const float* __restrict__ nb1,    // (128)
    const float* __restrict__ nW2,    // (128,128)
    const float* __restrict__ nb2,    // (128)
    const float* __restrict__ W_out,  // (128,128)
    const float* __restrict__ b_out,  // (128)
    float* __restrict__ out)          // (B,128)
{
    // h/tmp/ode stored TRANSPOSED as [batch n][k] f16 (256B rows), slot-swizzled
    __shared__ __align__(16) _Float16 hT[2][BN][NH];
    __shared__ __align__(16) _Float16 tmpT[BN][NH];
    __shared__ __align__(16) _Float16 odeT[BN][NH];
    __shared__ float sh_dt[NT];
    __shared__ uint  sh_mb[NT];

    const int tid  = threadIdx.x;
    const int w    = tid >> 6;     // wave 0..7: owns out-rows w*16..w*16+15
    const int lane = tid & 63;
    const int n    = lane & 15;    // A-row / B-col / D-col (batch)
    const int kg   = lane >> 4;    // k-group 0..3
    const int b0   = blockIdx.x * BN;

    // swizzled LDS offsets: 16B slot s at row n lives at slot s^(n&7)
    uint rdOff[4];
#pragma unroll
    for (int ks = 0; ks < 4; ++ks)
        rdOff[ks] = (uint)n * 256u + ((uint)((ks * 4 + kg) ^ (n & 7)) << 4);
    const uint wOff = (uint)n * 256u +
                      ((uint)(((w * 2) + (kg >> 1)) ^ (n & 7)) << 4) + (kg & 1) * 8;

    // ---- weights as MFMA A-fragments: lane holds W[base + n][ks*32 + kg*8 .. +8)
    f16x8 whrF[4], whzF[4], whnF[4], w1F[4], w2F[4];
#pragma unroll
    for (int ks = 0; ks < 4; ++ks) {
        const int c = ks * 32 + kg * 8;
        w1F[ks]  = ldWfrag(nW1  + (size_t)(w * 16 + n)       * NH + c);
        w2F[ks]  = ldWfrag(nW2  + (size_t)(w * 16 + n)       * NH + c);
        whrF[ks] = ldWfrag(W_hh + (size_t)(w * 16 + n)       * NH + c);
        whzF[ks] = ldWfrag(W_hh + (size_t)(w * 16 + n + 128) * NH + c);
        whnF[ks] = ldWfrag(W_hh + (size_t)(w * 16 + n + 256) * NH + c);
    }
    f16x8 wirF[2], wizF[2], winF[2];
#pragma unroll
    for (int k2 = 0; k2 < 2; ++k2) {
        const int c = k2 * 32 + kg * 8;
        wirF[k2] = ldWfrag(W_ih + (size_t)(w * 16 + n)       * ND + c);
        wizF[k2] = ldWfrag(W_ih + (size_t)(w * 16 + n + 128) * ND + c);
        winF[k2] = ldWfrag(W_ih + (size_t)(w * 16 + n + 256) * ND + c);
    }
    // biases at D rows j = w*16 + kg*4 + rr
    float bb1v[4], bb2v[4], brzr[4], brzz[4], binn[4], bhnn[4];
#pragma unroll
    for (int rr = 0; rr < 4; ++rr) {
        const int j = w * 16 + kg * 4 + rr;
        bb1v[rr] = nb1[j];
        bb2v[rr] = nb2[j];
        brzr[rr] = b_ih[j] + b_hh[j];
        brzz[rr] = b_ih[j + 128] + b_hh[j + 128];
        binn[rr] = b_ih[j + 256];
        bhnn[rr] = b_hh[j + 256];
    }

    // ---- stage dt + packed mask bits; zero h buffers
    for (int s = tid; s < NT; s += NTHR) {
        sh_dt[s] = (s == 0) ? 0.0f : (tps[s] - tps[s - 1]);
        uint wd = 0;
#pragma unroll
        for (int r = 0; r < BN; ++r)
            wd |= (uint)(mask[(size_t)(b0 + r) * NT + s] & 1) << r;
        sh_mb[s] = wd;
    }
    for (int i = tid; i < 2 * BN * NH / 2; i += NTHR) ((uint*)hT)[i] = 0u;
    __syncthreads();

    char* hT0 = (char*)hT;
    char* tB  = (char*)tmpT;
    char* oB  = (char*)odeT;

    // x prefetch (one step ahead): lane covers x[b0+n][s][k2*32 + kg*8 .. +8)
    const float* xrow = x + (size_t)(b0 + n) * NT * ND + kg * 8;
    float4 l0 = *(const float4*)(xrow);
    float4 l1 = *(const float4*)(xrow + 4);
    float4 l2 = *(const float4*)(xrow + 32);
    float4 l3 = *(const float4*)(xrow + 36);

    float hprev[4] = {0, 0, 0, 0}, hlast[4] = {0, 0, 0, 0};
    uint seen = 0;
    const f32x4 z4 = {0, 0, 0, 0};

    for (int s = 0; s < NT; ++s) {
        char* hbuf = hT0 + (size_t)(s & 1) * (BN * NH * 2);
        char* hnxt = hT0 + (size_t)((s & 1) ^ 1) * (BN * NH * 2);
        const float dt = sh_dt[s];
        const uint  mw = sh_mb[s];

        // pack current x; issue next-step prefetch
        const f16x8 xF0 = packx(l0, l1), xF1 = packx(l2, l3);
        const int sn = (s + 1 < NT) ? s + 1 : s;
        const float* xp = xrow + (size_t)sn * ND;
        l0 = *(const float4*)(xp);
        l1 = *(const float4*)(xp + 4);
        l2 = *(const float4*)(xp + 32);
        l3 = *(const float4*)(xp + 36);

        // input-gate GEMMs (independent of h chain)
        f32x4 Dgr = MFMA(wirF[0], xF0, z4); Dgr = MFMA(wirF[1], xF1, Dgr);
        f32x4 Dgz = MFMA(wizF[0], xF0, z4); Dgz = MFMA(wizF[1], xF1, Dgz);
        f32x4 Dgn = MFMA(winF[0], xF0, z4); Dgn = MFMA(winF[1], xF1, Dgn);

        float hode[4];
        const char* src;
        if (seen) {
            // stage 1: tmp = tanh(nW1 h + b1)
            f32x4 D1 = z4;
#pragma unroll
            for (int ks = 0; ks < 4; ++ks)
                D1 = MFMA(w1F[ks], *(const f16x8*)(hbuf + rdOff[ks]), D1);
            const uint t01 = pk(tanh_f(D1[0] + bb1v[0]), tanh_f(D1[1] + bb1v[1]));
            const uint t23 = pk(tanh_f(D1[2] + bb1v[2]), tanh_f(D1[3] + bb1v[3]));
            *(uint2*)(tB + wOff) = make_uint2(t01, t23);
            __syncthreads();

            // stage 2: h_ode = h + dte * (nW2 tmp + b2)   (dte per batch column)
            f32x4 D2 = z4;
#pragma unroll
            for (int ks = 0; ks < 4; ++ks)
                D2 = MFMA(w2F[ks], *(const f16x8*)(tB + rdOff[ks]), D2);
            const float dte = ((seen >> n) & 1u) ? dt : 0.0f;
#pragma unroll
            for (int rr = 0; rr < 4; ++rr)
                hode[rr] = hprev[rr] + dte * (D2[rr] + bb2v[rr]);
            *(uint2*)(oB + wOff) =
                make_uint2(pk(hode[0], hode[1]), pk(hode[2], hode[3]));
            __syncthreads();
            src = oB;
        } else {
#pragma unroll
            for (int rr = 0; rr < 4; ++rr) hode[rr] = hprev[rr];
            src = hbuf;
        }

        // stage 3: GRU recurrent GEMMs + gates
        f32x4 Dr = z4, Dz = z4, Dn = z4;
#pragma unroll
        for (int ks = 0; ks < 4; ++ks) {
            const f16x8 hB = *(const f16x8*)(src + rdOff[ks]);
            Dr = MFMA(whrF[ks], hB, Dr);
            Dz = MFMA(whzF[ks], hB, Dz);
            Dn = MFMA(whnF[ks], hB, Dn);
        }
        const uint mb = (mw >> n) & 1u;
#pragma unroll
        for (int rr = 0; rr < 4; ++rr) {
            const float r  = sigmoid_f(Dr[rr] + Dgr[rr] + brzr[rr]);
            const float zz = sigmoid_f(Dz[rr] + Dgz[rr] + brzz[rr]);
            const float nn = tanh_f(Dgn[rr] + binn[rr] + r * (Dn[rr] + bhnn[rr]));
            const float hv = mb ? (1.0f - zz) * nn + zz * hode[rr] : hode[rr];
            hprev[rr] = hv;
            hlast[rr] = mb ? hv : hlast[rr];
        }
        *(uint2*)(hnxt + wOff) =
            make_uint2(pk(hprev[0], hprev[1]), pk(hprev[2], hprev[3]));
        seen |= mw;
        __syncthreads();
    }

    // ---- epilogue: out = W_out @ h_last + b_out
    *(uint2*)(tB + wOff) =
        make_uint2(pk(hlast[0], hlast[1]), pk(hlast[2], hlast[3]));
    __syncthreads();
    f32x4 Do = z4;
#pragma unroll
    for (int ks = 0; ks < 4; ++ks) {
        const f16x8 a = ldWfrag(W_out + (size_t)(w * 16 + n) * NH + ks * 32 + kg * 8);
        Do = MFMA(a, *(const f16x8*)(tB + rdOff[ks]), Do);
    }
#pragma unroll
    for (int rr = 0; rr < 4; ++rr) {
        const int j = w * 16 + kg * 4 + rr;
        out[(size_t)(b0 + n) * NH + j] = Do[rr] + b_out[j];
    }
}

extern "C" void kernel_launch(void* const* d_in, const int* in_sizes, int n_in,
                              void* d_out, int out_size, void* d_ws, size_t ws_size,
                              hipStream_t stream) {
    const float* x     = (const float*)d_in[0];
    const float* tps   = (const float*)d_in[1];
    const int*   mask  = (const int*)  d_in[2];
    const float* W_ih  = (const float*)d_in[3];
    const float* W_hh  = (const float*)d_in[4];
    const float* b_ih  = (const float*)d_in[5];
    const float* b_hh  = (const float*)d_in[6];
    const float* nW1   = (const float*)d_in[7];
    const float* nb1   = (const float*)d_in[8];
    const float* nW2   = (const float*)d_in[9];
    const float* nb2   = (const float*)d_in[10];
    const float* W_out = (const float*)d_in[11];
    const float* b_out = (const float*)d_in[12];
    float* out = (float*)d_out;

    gruode_fused<<<dim3(NBLK), dim3(NTHR), 0, stream>>>(
        x, tps, mask, W_ih, W_hh, b_ih, b_hh,
        nW1, nb1, nW2, nb2, W_out, b_out, out);
}

// Round 7
// 1613.814 us; speedup vs baseline: 1.0083x; 1.0083x over previous
//
#include <hip/hip_runtime.h>

#define NB 256
#define NT 1000
#define ND 64
#define NH 128
#define NTHR 1024

typedef _Float16 h2 __attribute__((ext_vector_type(2)));

__device__ __forceinline__ uint pk(float a, float b) {
    return __builtin_bit_cast(uint, __builtin_amdgcn_cvt_pkrtz(a, b));
}
__device__ __forceinline__ float fdot2u(uint a, uint b, float c) {
#if __has_builtin(__builtin_amdgcn_fdot2)
    return __builtin_amdgcn_fdot2(__builtin_bit_cast(h2, a),
                                  __builtin_bit_cast(h2, b), c, false);
#else
    h2 ha = __builtin_bit_cast(h2, a), hb = __builtin_bit_cast(h2, b);
    return c + (float)ha.x * (float)hb.x + (float)ha.y * (float)hb.y;
#endif
}
__device__ __forceinline__ float sigmoid_f(float x) {
    float e = __builtin_amdgcn_exp2f(-1.4426950408889634f * x);
    return __builtin_amdgcn_rcpf(1.0f + e);
}
__device__ __forceinline__ float tanh_f(float x) {
    float e = __builtin_amdgcn_exp2f(-2.8853900817779268f * x);
    return 2.0f * __builtin_amdgcn_rcpf(1.0f + e) - 1.0f;
}
// load 8 consecutive f32, pack to 4 f16x2 regs
__device__ __forceinline__ void ld8(const float* p, uint* d) {
    const float4 A = *(const float4*)p;
    const float4 B = *(const float4*)(p + 4);
    d[0] = pk(A.x, A.y); d[1] = pk(A.z, A.w);
    d[2] = pk(B.x, B.y); d[3] = pk(B.z, B.w);
}
#define PIN(v) asm volatile("" : "+v"(v))

__global__
__attribute__((amdgpu_flat_work_group_size(NTHR, NTHR)))
__attribute__((amdgpu_waves_per_eu(4, 4)))   // pin to exactly 4 waves/EU -> 128-VGPR budget
void gruode_fused(
    const float* __restrict__ x,      // (B,T,D)
    const float* __restrict__ tps,    // (T)
    const int*   __restrict__ mask,   // (B,T)
    const float* __restrict__ W_ih,   // (384,64)
    const float* __restrict__ W_hh,   // (384,128)
    const float* __restrict__ b_ih,   // (384)
    const float* __restrict__ b_hh,   // (384)
    const float* __restrict__ nW1,    // (128,128)
    const float* __restrict__ nb1,    // (128)
    const float* __restrict__ nW2,    // (128,128)
    const float* __restrict__ nb2,    // (128)
    const float* __restrict__ W_out,  // (128,128)
    const float* __restrict__ b_out,  // (128)
    float* __restrict__ out)          // (B,128)
{
    __shared__ __align__(16) _Float16 sh_h[2][NH];
    __shared__ __align__(16) _Float16 sh_tmp[NH];
    __shared__ __align__(16) _Float16 sh_ode[NH];
    __shared__ float sh_eo[NH];
    __shared__ float sh_dt[NT];
    __shared__ int   sh_m[NT];

    const int tid = threadIdx.x;
    const int j   = tid >> 3;       // output row 0..127
    const int q   = tid & 7;        // K-eighth
    const int b   = blockIdx.x;
    const int kb  = q * 16;         // f16/f32 col base for H-dots
    const int qb  = q * 32;         // byte base within a 128-f16 row
    const int kbi = q * 8;          // f32 col base for D-dots
    // bank swizzle (verified 65K conflicts total in r4): chunk i reads 16B at
    // byte qb + w*16; q0-3 use chunk i, q4-7 use chunk i^1 -> the 8 q-groups
    // cover all 32 banks per instruction.
    const int w0  = (q >> 2) & 1;
    const int w1_ = w0 ^ 1;

    // ---- stage all weights into f16x2 registers (one-time), pre-swizzled ----
    uint W1r[2][4], W2r[2][4], Whr[2][4], Whz[2][4], Whn[2][4];
    uint wir[4], wiz[4], win[4];
    ld8(nW1  + (j      )*NH + kb + w0 *8, W1r[0]);
    ld8(nW1  + (j      )*NH + kb + w1_*8, W1r[1]);
    ld8(nW2  + (j      )*NH + kb + w0 *8, W2r[0]);
    ld8(nW2  + (j      )*NH + kb + w1_*8, W2r[1]);
    ld8(W_hh + (j      )*NH + kb + w0 *8, Whr[0]);
    ld8(W_hh + (j      )*NH + kb + w1_*8, Whr[1]);
    ld8(W_hh + (j + 128)*NH + kb + w0 *8, Whz[0]);
    ld8(W_hh + (j + 128)*NH + kb + w1_*8, Whz[1]);
    ld8(W_hh + (j + 256)*NH + kb + w0 *8, Whn[0]);
    ld8(W_hh + (j + 256)*NH + kb + w1_*8, Whn[1]);
    ld8(W_ih + (j      )*ND + kbi, wir);
    ld8(W_ih + (j + 128)*ND + kbi, wiz);
    ld8(W_ih + (j + 256)*ND + kbi, win);
    float bb1   = nb1[j];
    float bb2   = nb2[j];
    float brz_r = b_ih[j]       + b_hh[j];
    float brz_z = b_ih[j + 128] + b_hh[j + 128];
    float bin_n = b_ih[j + 256];
    float bhn_n = b_hh[j + 256];

#pragma unroll
    for (int i = 0; i < 2; ++i)
#pragma unroll
        for (int k = 0; k < 4; ++k) {
            PIN(W1r[i][k]); PIN(W2r[i][k]);
            PIN(Whr[i][k]); PIN(Whz[i][k]); PIN(Whn[i][k]);
        }
#pragma unroll
    for (int k = 0; k < 4; ++k) { PIN(wir[k]); PIN(wiz[k]); PIN(win[k]); }
    PIN(bb1); PIN(bb2); PIN(brz_r); PIN(brz_z); PIN(bin_n); PIN(bhn_n);

    // ---- stage dt / mask into LDS; init h ----
    for (int s = tid; s < NT; s += NTHR) {
        sh_dt[s] = (s == 0) ? 0.0f : (tps[s] - tps[s - 1]);
        sh_m[s]  = mask[b * NT + s];
    }
    if (tid < NH) sh_h[0][tid] = (_Float16)0.0f;
    __syncthreads();

    float hlast = 0.0f;
    int   seen  = 0;

    // software prefetch of x / dt / mask (one step ahead)
    const float* xbase = x + (size_t)b * NT * ND + kbi;
    float4 xa = *(const float4*)(xbase);
    float4 xb = *(const float4*)(xbase + 4);
    float dtc = sh_dt[0];
    int   mc  = sh_m[0];

    for (int s = 0; s < NT; ++s) {
        const int   cur = s & 1, nxt = cur ^ 1;
        const int   m   = mc;                    // uniform per block
        const float dte = seen ? dtc : 0.0f;     // r_fill freeze (uniform)

        // issue next-step prefetch (fully off critical path)
        const int sn = (s + 1 < NT) ? (s + 1) : s;
        const float* xr = xbase + (size_t)sn * ND;
        const float4 xa_n = *(const float4*)(xr);
        const float4 xb_n = *(const float4*)(xr + 4);
        const float dt_n = sh_dt[sn];
        const int   m_n  = sh_m[sn];

        // pack x and compute input-gate partial dots (independent of h chain)
        uint xh[4];
        xh[0] = pk(xa.x, xa.y); xh[1] = pk(xa.z, xa.w);
        xh[2] = pk(xb.x, xb.y); xh[3] = pk(xb.z, xb.w);
        float gr = 0.0f, gz = 0.0f, gn = 0.0f;
#pragma unroll
        for (int k = 0; k < 4; ++k) {
            gr = fdot2u(wir[k], xh[k], gr);
            gz = fdot2u(wiz[k], xh[k], gz);
            gn = fdot2u(win[k], xh[k], gn);
        }

        const float hj = (float)sh_h[cur][j];
        float hode_j;
        const _Float16* hsrc;

        if (dte != 0.0f) {
            // stage 1: tmp = tanh(W1 h + b1)   (2 partial chains for ILP)
            float a1a = 0.0f, a1b = 0.0f;
            {
                const uint4 hv = *(const uint4*)((const char*)&sh_h[cur][0] + qb + w0*16);
                a1a = fdot2u(W1r[0][0], hv.x, a1a); a1b = fdot2u(W1r[0][1], hv.y, a1b);
                a1a = fdot2u(W1r[0][2], hv.z, a1a); a1b = fdot2u(W1r[0][3], hv.w, a1b);
            }
            {
                const uint4 hv = *(const uint4*)((const char*)&sh_h[cur][0] + qb + w1_*16);
                a1a = fdot2u(W1r[1][0], hv.x, a1a); a1b = fdot2u(W1r[1][1], hv.y, a1b);
                a1a = fdot2u(W1r[1][2], hv.z, a1a); a1b = fdot2u(W1r[1][3], hv.w, a1b);
            }
            float a1 = a1a + a1b;
            a1 += __shfl_xor(a1, 1); a1 += __shfl_xor(a1, 2); a1 += __shfl_xor(a1, 4);
            if (q == 0) sh_tmp[j] = (_Float16)tanh_f(a1 + bb1);
            __syncthreads();

            // stage 2: h_ode = h + dt * (W2 tmp + b2)
            float a2a = 0.0f, a2b = 0.0f;
            {
                const uint4 hv = *(const uint4*)((const char*)sh_tmp + qb + w0*16);
                a2a = fdot2u(W2r[0][0], hv.x, a2a); a2b = fdot2u(W2r[0][1], hv.y, a2b);
                a2a = fdot2u(W2r[0][2], hv.z, a2a); a2b = fdot2u(W2r[0][3], hv.w, a2b);
            }
            {
                const uint4 hv = *(const uint4*)((const char*)sh_tmp + qb + w1_*16);
                a2a = fdot2u(W2r[1][0], hv.x, a2a); a2b = fdot2u(W2r[1][1], hv.y, a2b);
                a2a = fdot2u(W2r[1][2], hv.z, a2a); a2b = fdot2u(W2r[1][3], hv.w, a2b);
            }
            float a2 = a2a + a2b;
            a2 += __shfl_xor(a2, 1); a2 += __shfl_xor(a2, 2); a2 += __shfl_xor(a2, 4);
            hode_j = hj + dte * (a2 + bb2);
            if (q == 0) sh_ode[j] = (_Float16)hode_j;
            __syncthreads();
            hsrc = sh_ode;
        } else {
            hode_j = hj;
            hsrc = &sh_h[cur][0];
        }

        // stage 3: GRU cell recurrent dots (3 chains)
        float ar = 0.0f, az = 0.0f, an = 0.0f;
        {
            const uint4 hv = *(const uint4*)((const char*)hsrc + qb + w0*16);
            ar = fdot2u(Whr[0][0], hv.x, ar); ar = fdot2u(Whr[0][1], hv.y, ar);
            ar = fdot2u(Whr[0][2], hv.z, ar); ar = fdot2u(Whr[0][3], hv.w, ar);
            az = fdot2u(Whz[0][0], hv.x, az); az = fdot2u(Whz[0][1], hv.y, az);
            az = fdot2u(Whz[0][2], hv.z, az); az = fdot2u(Whz[0][3], hv.w, az);
            an = fdot2u(Whn[0][0], hv.x, an); an = fdot2u(Whn[0][1], hv.y, an);
            an = fdot2u(Whn[0][2], hv.z, an); an = fdot2u(Whn[0][3], hv.w, an);
        }
        {
            const uint4 hv = *(const uint4*)((const char*)hsrc + qb + w1_*16);
            ar = fdot2u(Whr[1][0], hv.x, ar); ar = fdot2u(Whr[1][1], hv.y, ar);
            ar = fdot2u(Whr[1][2], hv.z, ar); ar = fdot2u(Whr[1][3], hv.w, ar);
            az = fdot2u(Whz[1][0], hv.x, az); az = fdot2u(Whz[1][1], hv.y, az);
            az = fdot2u(Whz[1][2], hv.z, az); az = fdot2u(Whz[1][3], hv.w, az);
            an = fdot2u(Whn[1][0], hv.x, an); an = fdot2u(Whn[1][1], hv.y, an);
            an = fdot2u(Whn[1][2], hv.z, an); an = fdot2u(Whn[1][3], hv.w, an);
        }
        float sr = ar + gr, sz = az + gz;
        sr += __shfl_xor(sr, 1); sr += __shfl_xor(sr, 2); sr += __shfl_xor(sr, 4);
        sz += __shfl_xor(sz, 1); sz += __shfl_xor(sz, 2); sz += __shfl_xor(sz, 4);
        an += __shfl_xor(an, 1); an += __shfl_xor(an, 2); an += __shfl_xor(an, 4);
        gn += __shfl_xor(gn, 1); gn += __shfl_xor(gn, 2); gn += __shfl_xor(gn, 4);

        const float r = sigmoid_f(sr + brz_r);
        const float z = sigmoid_f(sz + brz_z);
        const float n = tanh_f(gn + bin_n + r * (an + bhn_n));
        const float hnew = m ? ((1.0f - z) * n + z * hode_j) : hode_j;

        if (q == 0) sh_h[nxt][j] = (_Float16)hnew;  // ping-pong write
        if (m) hlast = hnew;
        seen |= m;
        xa = xa_n; xb = xb_n; dtc = dt_n; mc = m_n;
        __syncthreads();
    }

    // epilogue (f32): out = W_out @ h_last + b_out
    if (q == 0) sh_eo[j] = hlast;
    __syncthreads();
    float ao = 0.0f;
#pragma unroll
    for (int i = 0; i < 4; ++i) {
        const float4 wv = *(const float4*)(W_out + j*NH + kb + i*4);
        const float4 hv = *(const float4*)(sh_eo + kb + i*4);
        ao += wv.x*hv.x + wv.y*hv.y + wv.z*hv.z + wv.w*hv.w;
    }
    ao += __shfl_xor(ao, 1); ao += __shfl_xor(ao, 2); ao += __shfl_xor(ao, 4);
    if (q == 0) out[b*NH + j] = ao + b_out[j];
}

extern "C" void kernel_launch(void* const* d_in, const int* in_sizes, int n_in,
                              void* d_out, int out_size, void* d_ws, size_t ws_size,
                              hipStream_t stream) {
    const float* x     = (const float*)d_in[0];
    const float* tps   = (const float*)d_in[1];
    const int*   mask  = (const int*)  d_in[2];
    const float* W_ih  = (const float*)d_in[3];
    const float* W_hh  = (const float*)d_in[4];
    const float* b_ih  = (const float*)d_in[5];
    const float* b_hh  = (const float*)d_in[6];
    const float* nW1   = (const float*)d_in[7];
    const float* nb1   = (const float*)d_in[8];
    const float* nW2   = (const float*)d_in[9];
    const float* nb2   = (const float*)d_in[10];
    const float* W_out = (const float*)d_in[11];
    const float* b_out = (const float*)d_in[12];
    float* out = (float*)d_out;

    gruode_fused<<<dim3(NB), dim3(NTHR), 0, stream>>>(
        x, tps, mask, W_ih, W_hh, b_ih, b_hh,
        nW1, nb1, nW2, nb2, W_out, b_out, out);
}

// Round 8
// 1375.158 us; speedup vs baseline: 1.1833x; 1.1735x over previous
//
#include <hip/hip_runtime.h>

#define NB 256
#define NT 1000
#define ND 64
#define NH 128

typedef _Float16 h2 __attribute__((ext_vector_type(2)));

static __device__ __forceinline__ uint pk(float a, float b) {
    return __builtin_bit_cast(uint, __builtin_amdgcn_cvt_pkrtz(a, b));
}
static __device__ __forceinline__ float fdot2u(uint a, uint b, float c) {
#if __has_builtin(__builtin_amdgcn_fdot2)
    return __builtin_amdgcn_fdot2(__builtin_bit_cast(h2, a),
                                  __builtin_bit_cast(h2, b), c, false);
#else
    h2 ha = __builtin_bit_cast(h2, a), hb = __builtin_bit_cast(h2, b);
    return c + (float)ha.x * (float)hb.x + (float)ha.y * (float)hb.y;
#endif
}
static __device__ __forceinline__ float f16lo(uint u) {
    return (float)__builtin_bit_cast(h2, u).x;
}
static __device__ __forceinline__ float f16hi(uint u) {
    return (float)__builtin_bit_cast(h2, u).y;
}
static __device__ __forceinline__ float sigmoid_f(float x) {
    float e = __builtin_amdgcn_exp2f(-1.4426950408889634f * x);
    return __builtin_amdgcn_rcpf(1.0f + e);
}
static __device__ __forceinline__ float tanh_f(float x) {
    float e = __builtin_amdgcn_exp2f(-2.8853900817779268f * x);
    return 2.0f * __builtin_amdgcn_rcpf(1.0f + e) - 1.0f;
}
// load 8 consecutive f32, pack to 4 f16x2 regs
static __device__ __forceinline__ void ld8(const float* p, uint* d) {
    const float4 A = *(const float4*)p;
    const float4 B = *(const float4*)(p + 4);
    d[0] = pk(A.x, A.y); d[1] = pk(A.z, A.w);
    d[2] = pk(B.x, B.y); d[3] = pk(B.z, B.w);
}
#define PIN(v) asm volatile("" : "+v"(v))

// ---------- gi precompute: gi[s][b][j][4] (f16) = W_ih @ x, gates 0..2 ----------
__global__ __launch_bounds__(384) void gi_pre(
    const float* __restrict__ x,      // (B,T,D)
    const float* __restrict__ W_ih,   // (384,64)
    ushort* __restrict__ gi)
{
    __shared__ uint xt[128][32];      // f16-packed x tile (16 KB)
    const int tid = threadIdx.x;      // 0..383 = W_ih row
    const int b   = blockIdx.x;
    uint wr[32];
    const float* wrow = W_ih + (size_t)tid * ND;
#pragma unroll
    for (int k = 0; k < 8; ++k) ld8(wrow + k * 8, wr + k * 4);
    const int g = tid >> 7, j = tid & 127;

    for (int t0 = 0; t0 < NT; t0 += 128) {
        const int ttn = (NT - t0 < 128) ? (NT - t0) : 128;
        __syncthreads();
        for (int i = tid; i < ttn * 32; i += 384) {
            const int t = i >> 5, c = i & 31;
            const float2 v = *(const float2*)(x + ((size_t)b * NT + t0 + t) * ND + c * 2);
            xt[t][c] = pk(v.x, v.y);
        }
        __syncthreads();
        for (int t = 0; t < ttn; ++t) {
            const uint4* xr = (const uint4*)&xt[t][0];
            float acc = 0.0f;
#pragma unroll
            for (int k4 = 0; k4 < 8; ++k4) {
                const uint4 hv = xr[k4];
                acc = fdot2u(wr[k4*4+0], hv.x, acc);
                acc = fdot2u(wr[k4*4+1], hv.y, acc);
                acc = fdot2u(wr[k4*4+2], hv.z, acc);
                acc = fdot2u(wr[k4*4+3], hv.w, acc);
            }
            gi[(((size_t)(t0 + t) * NB + b) * NH + j) * 4 + g] =
                __builtin_bit_cast(ushort, (_Float16)acc);
        }
    }
}

// ---------- fused scan ----------
template<int GI>
__global__
__attribute__((amdgpu_flat_work_group_size(512, 512)))
__attribute__((amdgpu_waves_per_eu(2, 2)))
void gruode_scan(
    const float* __restrict__ x,      // (B,T,D)  (GI=0 path only)
    const float* __restrict__ tps,    // (T)
    const int*   __restrict__ mask,   // (B,T)
    const float* __restrict__ W_ih,   // (384,64)  (GI=0 path only)
    const float* __restrict__ W_hh,   // (384,128)
    const float* __restrict__ b_ih,   // (384)
    const float* __restrict__ b_hh,   // (384)
    const float* __restrict__ nW1,    // (128,128)
    const float* __restrict__ nb1,    // (128)
    const float* __restrict__ nW2,    // (128,128)
    const float* __restrict__ nb2,    // (128)
    const float* __restrict__ W_out,  // (128,128)
    const float* __restrict__ b_out,  // (128)
    const ushort* __restrict__ gi,    // (T,B,128,4) f16 (GI=1)
    float* __restrict__ out)          // (B,128)
{
    __shared__ __align__(16) _Float16 sh_h[2][NH];
    __shared__ __align__(16) _Float16 sh_tmp[NH];
    __shared__ __align__(16) _Float16 sh_ode[NH];
    __shared__ float sh_eo[NH];
    __shared__ float sh_dt[NT];
    __shared__ int   sh_m[NT];

    const int tid = threadIdx.x;
    const int j   = tid >> 2;   // output row 0..127
    const int q   = tid & 3;    // K-quarter
    const int b   = blockIdx.x;
    const int kb  = q * 32;     // f16 col base for H-dots
    const int qb  = q * 64;     // byte base within a 128-f16 row

    // bank rotation (verified 0 conflicts, r3/r5): chunk i -> byte qb + WSEL(i)*16
#define WSEL(i) (((i) + (q >> 1)) & 3)

    // ---- stage recurrent weights into f16x2 registers, pre-rotated ----
    uint w1[4][4], w2[4][4], whr[4][4], whz[4][4], whn[4][4];
#pragma unroll
    for (int i = 0; i < 4; ++i) {
        const int c = kb + (WSEL(i) << 3);
        ld8(nW1  + (j      )*NH + c, w1[i]);
        ld8(nW2  + (j      )*NH + c, w2[i]);
        ld8(W_hh + (j      )*NH + c, whr[i]);
        ld8(W_hh + (j + 128)*NH + c, whz[i]);
        ld8(W_hh + (j + 256)*NH + c, whn[i]);
    }
    uint wir[8], wiz[8], win[8];
    if constexpr (!GI) {
        const int kbi = q * 16;
        ld8(W_ih + (j      )*ND + kbi,     wir);
        ld8(W_ih + (j      )*ND + kbi + 8, wir + 4);
        ld8(W_ih + (j + 128)*ND + kbi,     wiz);
        ld8(W_ih + (j + 128)*ND + kbi + 8, wiz + 4);
        ld8(W_ih + (j + 256)*ND + kbi,     win);
        ld8(W_ih + (j + 256)*ND + kbi + 8, win + 4);
    }
    float bb1   = nb1[j];
    float bb2   = nb2[j];
    float brz_r = b_ih[j]       + b_hh[j];
    float brz_z = b_ih[j + 128] + b_hh[j + 128];
    float bin_n = b_ih[j + 256];
    float bhn_n = b_hh[j + 256];

#pragma unroll
    for (int i = 0; i < 4; ++i)
#pragma unroll
        for (int k = 0; k < 4; ++k) {
            PIN(w1[i][k]); PIN(w2[i][k]);
            PIN(whr[i][k]); PIN(whz[i][k]); PIN(whn[i][k]);
        }
    PIN(bb1); PIN(bb2); PIN(brz_r); PIN(brz_z); PIN(bin_n); PIN(bhn_n);

    // ---- stage dt / mask into LDS; init h ----
    for (int s = tid; s < NT; s += 512) {
        sh_dt[s] = (s == 0) ? 0.0f : (tps[s] - tps[s - 1]);
        sh_m[s]  = mask[b * NT + s];
    }
    if (tid < NH) sh_h[0][tid] = (_Float16)0.0f;
    __syncthreads();

    float hlast = 0.0f;
    int   seen  = 0;

    // 1-step-ahead prefetch state
    const uint2* gp = (const uint2*)gi + ((size_t)b * NH + j); // stride NB*NH per s
    const float* xbase = x + (size_t)b * NT * ND + q * 16;
    uint2  gc;
    float4 xc0, xc1, xc2, xc3;
    if constexpr (GI) {
        gc = gp[0];
    } else {
        xc0 = *(const float4*)(xbase);
        xc1 = *(const float4*)(xbase + 4);
        xc2 = *(const float4*)(xbase + 8);
        xc3 = *(const float4*)(xbase + 12);
    }
    float dtc = sh_dt[0];
    int   mc  = sh_m[0];

    for (int s = 0; s < NT; ++s) {
        const int   cur = s & 1, nxt = cur ^ 1;
        const int   m   = mc;                    // uniform per block
        const float dte = seen ? dtc : 0.0f;     // r_fill freeze (uniform)

        // issue next-step prefetch (off critical path)
        const int sn = (s + 1 < NT) ? (s + 1) : s;
        uint2  gn_;
        float4 xn0, xn1, xn2, xn3;
        if constexpr (GI) {
            gn_ = gp[(size_t)sn * (NB * NH)];
        } else {
            const float* xr = xbase + (size_t)sn * ND;
            xn0 = *(const float4*)(xr);
            xn1 = *(const float4*)(xr + 4);
            xn2 = *(const float4*)(xr + 8);
            xn3 = *(const float4*)(xr + 12);
        }
        const float dt_n = sh_dt[sn];
        const int   m_n  = sh_m[sn];

        // input-gate contributions
        float grf, gzf, gnf;
        if constexpr (GI) {
            grf = f16lo(gc.x); gzf = f16hi(gc.x); gnf = f16lo(gc.y); // full dots
        } else {
            uint xh[8];
            xh[0] = pk(xc0.x, xc0.y); xh[1] = pk(xc0.z, xc0.w);
            xh[2] = pk(xc1.x, xc1.y); xh[3] = pk(xc1.z, xc1.w);
            xh[4] = pk(xc2.x, xc2.y); xh[5] = pk(xc2.z, xc2.w);
            xh[6] = pk(xc3.x, xc3.y); xh[7] = pk(xc3.z, xc3.w);
            grf = gzf = gnf = 0.0f;
#pragma unroll
            for (int k = 0; k < 8; ++k) {
                grf = fdot2u(wir[k], xh[k], grf);
                gzf = fdot2u(wiz[k], xh[k], gzf);
                gnf = fdot2u(win[k], xh[k], gnf);
            }
        }

        const float hj = (float)sh_h[cur][j];
        float hode_j;
        const _Float16* hsrc;

        if (dte != 0.0f) {
            // stage 1: tmp = tanh(W1 h + b1)
            float a1a = 0.0f, a1b = 0.0f;
#pragma unroll
            for (int i = 0; i < 4; ++i) {
                const uint4 hv = *(const uint4*)((const char*)&sh_h[cur][0] + qb + WSEL(i)*16);
                float& acc = (i & 1) ? a1b : a1a;
                acc = fdot2u(w1[i][0], hv.x, acc); acc = fdot2u(w1[i][1], hv.y, acc);
                acc = fdot2u(w1[i][2], hv.z, acc); acc = fdot2u(w1[i][3], hv.w, acc);
            }
            float a1 = a1a + a1b;
            a1 += __shfl_xor(a1, 1); a1 += __shfl_xor(a1, 2);
            if (q == 0) sh_tmp[j] = (_Float16)tanh_f(a1 + bb1);
            __syncthreads();

            // stage 2: h_ode = h + dt * (W2 tmp + b2)
            float a2a = 0.0f, a2b = 0.0f;
#pragma unroll
            for (int i = 0; i < 4; ++i) {
                const uint4 hv = *(const uint4*)((const char*)sh_tmp + qb + WSEL(i)*16);
                float& acc = (i & 1) ? a2b : a2a;
                acc = fdot2u(w2[i][0], hv.x, acc); acc = fdot2u(w2[i][1], hv.y, acc);
                acc = fdot2u(w2[i][2], hv.z, acc); acc = fdot2u(w2[i][3], hv.w, acc);
            }
            float a2 = a2a + a2b;
            a2 += __shfl_xor(a2, 1); a2 += __shfl_xor(a2, 2);
            hode_j = hj + dte * (a2 + bb2);
            if (q == 0) sh_ode[j] = (_Float16)hode_j;
            __syncthreads();
            hsrc = sh_ode;
        } else {
            hode_j = hj;
            hsrc = &sh_h[cur][0];
        }

        // stage 3: GRU recurrent dots (3 chains)
        float ar = 0.0f, az = 0.0f, an = 0.0f;
#pragma unroll
        for (int i = 0; i < 4; ++i) {
            const uint4 hv = *(const uint4*)((const char*)hsrc + qb + WSEL(i)*16);
            ar = fdot2u(whr[i][0], hv.x, ar); ar = fdot2u(whr[i][1], hv.y, ar);
            ar = fdot2u(whr[i][2], hv.z, ar); ar = fdot2u(whr[i][3], hv.w, ar);
            az = fdot2u(whz[i][0], hv.x, az); az = fdot2u(whz[i][1], hv.y, az);
            az = fdot2u(whz[i][2], hv.z, az); az = fdot2u(whz[i][3], hv.w, az);
            an = fdot2u(whn[i][0], hv.x, an); an = fdot2u(whn[i][1], hv.y, an);
            an = fdot2u(whn[i][2], hv.z, an); an = fdot2u(whn[i][3], hv.w, an);
        }
        float r, z, n;
        if constexpr (GI) {
            ar += __shfl_xor(ar, 1); ar += __shfl_xor(ar, 2);
            az += __shfl_xor(az, 1); az += __shfl_xor(az, 2);
            an += __shfl_xor(an, 1); an += __shfl_xor(an, 2);
            r = sigmoid_f(ar + grf + brz_r);
            z = sigmoid_f(az + gzf + brz_z);
            n = tanh_f(gnf + bin_n + r * (an + bhn_n));
        } else {
            float sr = ar + grf, sz = az + gzf, gn2 = gnf;
            sr += __shfl_xor(sr, 1); sr += __shfl_xor(sr, 2);
            sz += __shfl_xor(sz, 1); sz += __shfl_xor(sz, 2);
            an += __shfl_xor(an, 1); an += __shfl_xor(an, 2);
            gn2 += __shfl_xor(gn2, 1); gn2 += __shfl_xor(gn2, 2);
            r = sigmoid_f(sr + brz_r);
            z = sigmoid_f(sz + brz_z);
            n = tanh_f(gn2 + bin_n + r * (an + bhn_n));
        }
        const float hnew = m ? ((1.0f - z) * n + z * hode_j) : hode_j;

        if (q == 0) sh_h[nxt][j] = (_Float16)hnew;  // ping-pong write
        if (m) hlast = hnew;
        seen |= m;
        if constexpr (GI) { gc = gn_; }
        else { xc0 = xn0; xc1 = xn1; xc2 = xn2; xc3 = xn3; }
        dtc = dt_n; mc = m_n;
        __syncthreads();
    }

    // epilogue (f32): out = W_out @ h_last + b_out
    if (q == 0) sh_eo[j] = hlast;
    __syncthreads();
    float ao = 0.0f;
#pragma unroll
    for (int i = 0; i < 8; ++i) {
        const int c = kb + (((i + 2 * q) & 7) << 2);
        const float4 wv = *(const float4*)(W_out + j*NH + c);
        const float4 hv = *(const float4*)(sh_eo + c);
        ao += wv.x*hv.x + wv.y*hv.y + wv.z*hv.z + wv.w*hv.w;
    }
    ao += __shfl_xor(ao, 1); ao += __shfl_xor(ao, 2);
    if (q == 0) out[b*NH + j] = ao + b_out[j];
}

extern "C" void kernel_launch(void* const* d_in, const int* in_sizes, int n_in,
                              void* d_out, int out_size, void* d_ws, size_t ws_size,
                              hipStream_t stream) {
    const float* x     = (const float*)d_in[0];
    const float* tps   = (const float*)d_in[1];
    const int*   mask  = (const int*)  d_in[2];
    const float* W_ih  = (const float*)d_in[3];
    const float* W_hh  = (const float*)d_in[4];
    const float* b_ih  = (const float*)d_in[5];
    const float* b_hh  = (const float*)d_in[6];
    const float* nW1   = (const float*)d_in[7];
    const float* nb1   = (const float*)d_in[8];
    const float* nW2   = (const float*)d_in[9];
    const float* nb2   = (const float*)d_in[10];
    const float* W_out = (const float*)d_in[11];
    const float* b_out = (const float*)d_in[12];
    float* out = (float*)d_out;

    const size_t ws_needed = (size_t)NT * NB * NH * 4 * sizeof(ushort); // 262,144,000
    if (ws_size >= ws_needed) {
        ushort* gi = (ushort*)d_ws;
        gi_pre<<<dim3(NB), dim3(384), 0, stream>>>(x, W_ih, gi);
        gruode_scan<1><<<dim3(NB), dim3(512), 0, stream>>>(
            x, tps, mask, W_ih, W_hh, b_ih, b_hh,
            nW1, nb1, nW2, nb2, W_out, b_out, gi, out);
    } else {
        gruode_scan<0><<<dim3(NB), dim3(512), 0, stream>>>(
            x, tps, mask, W_ih, W_hh, b_ih, b_hh,
            nW1, nb1, nW2, nb2, W_out, b_out, nullptr, out);
    }
}

// Round 9
// 1354.305 us; speedup vs baseline: 1.2015x; 1.0154x over previous
//
#include <hip/hip_runtime.h>

#define NB 256
#define NT 1000
#define ND 64
#define NH 128

typedef _Float16 h2 __attribute__((ext_vector_type(2)));

static __device__ __forceinline__ uint pk(float a, float b) {
    return __builtin_bit_cast(uint, __builtin_amdgcn_cvt_pkrtz(a, b));
}
static __device__ __forceinline__ float fdot2u(uint a, uint b, float c) {
#if __has_builtin(__builtin_amdgcn_fdot2)
    return __builtin_amdgcn_fdot2(__builtin_bit_cast(h2, a),
                                  __builtin_bit_cast(h2, b), c, false);
#else
    h2 ha = __builtin_bit_cast(h2, a), hb = __builtin_bit_cast(h2, b);
    return c + (float)ha.x * (float)hb.x + (float)ha.y * (float)hb.y;
#endif
}
static __device__ __forceinline__ float f16lo(uint u) {
    return (float)__builtin_bit_cast(h2, u).x;
}
static __device__ __forceinline__ float f16hi(uint u) {
    return (float)__builtin_bit_cast(h2, u).y;
}
static __device__ __forceinline__ float sigmoid_f(float x) {
    float e = __builtin_amdgcn_exp2f(-1.4426950408889634f * x);
    return __builtin_amdgcn_rcpf(1.0f + e);
}
static __device__ __forceinline__ float tanh_f(float x) {
    float e = __builtin_amdgcn_exp2f(-2.8853900817779268f * x);
    return 2.0f * __builtin_amdgcn_rcpf(1.0f + e) - 1.0f;
}
// quad (lanes 0-3 of each group) butterfly sum via DPP: no LDS, ~2cy/op
static __device__ __forceinline__ float qsum(float v) {
    int a = __builtin_amdgcn_update_dpp(0, __builtin_bit_cast(int, v),
                                        0xB1, 0xF, 0xF, true); // quad_perm(1,0,3,2)
    v += __builtin_bit_cast(float, a);
    int b = __builtin_amdgcn_update_dpp(0, __builtin_bit_cast(int, v),
                                        0x4E, 0xF, 0xF, true); // quad_perm(2,3,0,1)
    v += __builtin_bit_cast(float, b);
    return v;
}
// load 8 consecutive f32, pack to 4 f16x2 regs
static __device__ __forceinline__ void ld8(const float* p, uint* d) {
    const float4 A = *(const float4*)p;
    const float4 B = *(const float4*)(p + 4);
    d[0] = pk(A.x, A.y); d[1] = pk(A.z, A.w);
    d[2] = pk(B.x, B.y); d[3] = pk(B.z, B.w);
}
#define PIN(v) asm volatile("" : "+v"(v))
// raw barrier: orders LDS only; does NOT drain vmcnt -> global prefetch stays in flight
#define WAVEBAR() asm volatile("s_waitcnt lgkmcnt(0)\n\ts_barrier" ::: "memory")

// ---------- gi precompute: gi2[t][b][j] = {pk(g_r,g_z), pk(g_n,0)} ----------
__global__ __launch_bounds__(128) void gi_pre(
    const float* __restrict__ x,      // (B,T,D)
    const float* __restrict__ W_ih,   // (384,64)
    uint2* __restrict__ gi2)          // (T,B,NH)
{
    const int j = threadIdx.x;        // 0..127
    const int b = blockIdx.x;
    const int t0 = blockIdx.y * 125;
    const int t1 = (t0 + 125 < NT) ? t0 + 125 : NT;

    uint wir[8], wiz[8], win[8];
    ld8(W_ih + (size_t)(j      ) * ND,     wir);
    ld8(W_ih + (size_t)(j      ) * ND + 8, wir + 4);
    ld8(W_ih + (size_t)(j + 128) * ND,     wiz);
    ld8(W_ih + (size_t)(j + 128) * ND + 8, wiz + 4);
    ld8(W_ih + (size_t)(j + 256) * ND,     win);
    ld8(W_ih + (size_t)(j + 256) * ND + 8, win + 4);

    for (int t = t0; t < t1; ++t) {
        const float* xr = x + ((size_t)b * NT + t) * ND;
        uint xh[8];
#pragma unroll
        for (int k = 0; k < 4; ++k) {
            const float4 a = *(const float4*)(xr + k * 16);
            const float4 c = *(const float4*)(xr + k * 16 + 4);
            xh[k * 2]     = pk(a.x, a.y);
            xh[k * 2 + 1] = pk(a.z, a.w);
            // reuse: pack next 8 too
            (void)c;
            xh[k * 2]     = pk(a.x, a.y);
            xh[k * 2 + 1] = pk(a.z, a.w);
        }
        // full 64-wide pack (redo cleanly: 8 chunks of 8B)
        {
            const float4 a0 = *(const float4*)(xr);
            const float4 a1 = *(const float4*)(xr + 4);
            const float4 a2 = *(const float4*)(xr + 8);
            const float4 a3 = *(const float4*)(xr + 12);
            const float4 a4 = *(const float4*)(xr + 16);
            const float4 a5 = *(const float4*)(xr + 20);
            const float4 a6 = *(const float4*)(xr + 24);
            const float4 a7 = *(const float4*)(xr + 28);
            uint xl[16];
            xl[0]=pk(a0.x,a0.y); xl[1]=pk(a0.z,a0.w); xl[2]=pk(a1.x,a1.y); xl[3]=pk(a1.z,a1.w);
            xl[4]=pk(a2.x,a2.y); xl[5]=pk(a2.z,a2.w); xl[6]=pk(a3.x,a3.y); xl[7]=pk(a3.z,a3.w);
            xl[8]=pk(a4.x,a4.y); xl[9]=pk(a4.z,a4.w); xl[10]=pk(a5.x,a5.y); xl[11]=pk(a5.z,a5.w);
            xl[12]=pk(a6.x,a6.y); xl[13]=pk(a6.z,a6.w); xl[14]=pk(a7.x,a7.y); xl[15]=pk(a7.z,a7.w);
            const float4 b0 = *(const float4*)(xr + 32);
            const float4 b1 = *(const float4*)(xr + 36);
            const float4 b2 = *(const float4*)(xr + 40);
            const float4 b3 = *(const float4*)(xr + 44);
            const float4 b4 = *(const float4*)(xr + 48);
            const float4 b5 = *(const float4*)(xr + 52);
            const float4 b6 = *(const float4*)(xr + 56);
            const float4 b7 = *(const float4*)(xr + 60);
            uint xm[16];
            xm[0]=pk(b0.x,b0.y); xm[1]=pk(b0.z,b0.w); xm[2]=pk(b1.x,b1.y); xm[3]=pk(b1.z,b1.w);
            xm[4]=pk(b2.x,b2.y); xm[5]=pk(b2.z,b2.w); xm[6]=pk(b3.x,b3.y); xm[7]=pk(b3.z,b3.w);
            xm[8]=pk(b4.x,b4.y); xm[9]=pk(b4.z,b4.w); xm[10]=pk(b5.x,b5.y); xm[11]=pk(b5.z,b5.w);
            xm[12]=pk(b6.x,b6.y); xm[13]=pk(b6.z,b6.w); xm[14]=pk(b7.x,b7.y); xm[15]=pk(b7.z,b7.w);
            // wait: W rows are 64 wide (32 u32); xl+xm cover 64 floats = 32 u32
            float gr = 0.0f, gz = 0.0f, gn = 0.0f;
#pragma unroll
            for (int k = 0; k < 8; ++k) {
                // wir has 8 u32 covering 16 f16?? -> W row is 64 f16 = 32 u32.
                gr = fdot2u(wir[k & 7], (k < 8) ? xl[k] : xm[k - 8], gr);
                (void)gz; (void)gn;
            }
            // The above is wrong-sized; real dot below over 32 u32 chunks:
            gr = 0.0f; gz = 0.0f; gn = 0.0f;
            // reload weights wide (32 u32 each) from LDS-free registers is too big;
            // instead accumulate in 4 passes of 8 u32 using on-the-fly weight loads
            const float* w0 = W_ih + (size_t)(j      ) * ND;
            const float* w1p = W_ih + (size_t)(j + 128) * ND;
            const float* w2p = W_ih + (size_t)(j + 256) * ND;
#pragma unroll
            for (int k = 0; k < 16; ++k) {
                const uint xv = xl[k];
                const float2 wa = *(const float2*)(w0 + k * 2);
                const float2 wb = *(const float2*)(w1p + k * 2);
                const float2 wc = *(const float2*)(w2p + k * 2);
                gr = fdot2u(pk(wa.x, wa.y), xv, gr);
                gz = fdot2u(pk(wb.x, wb.y), xv, gz);
                gn = fdot2u(pk(wc.x, wc.y), xv, gn);
            }
#pragma unroll
            for (int k = 0; k < 16; ++k) {
                const uint xv = xm[k];
                const float2 wa = *(const float2*)(w0 + 32 + k * 2);
                const float2 wb = *(const float2*)(w1p + 32 + k * 2);
                const float2 wc = *(const float2*)(w2p + 32 + k * 2);
                gr = fdot2u(pk(wa.x, wa.y), xv, gr);
                gz = fdot2u(pk(wb.x, wb.y), xv, gz);
                gn = fdot2u(pk(wc.x, wc.y), xv, gn);
            }
            gi2[((size_t)t * NB + b) * NH + j] = make_uint2(pk(gr, gz), pk(gn, 0.0f));
        }
    }
}

// ---------- fused scan ----------
template<int GI>
__global__
__attribute__((amdgpu_flat_work_group_size(512, 512)))
__attribute__((amdgpu_waves_per_eu(2, 2)))
void gruode_scan(
    const float* __restrict__ x,      // (B,T,D)  (GI=0 path only)
    const float* __restrict__ tps,    // (T)
    const int*   __restrict__ mask,   // (B,T)
    const float* __restrict__ W_ih,   // (384,64)  (GI=0 path only)
    const float* __restrict__ W_hh,   // (384,128)
    const float* __restrict__ b_ih,   // (384)
    const float* __restrict__ b_hh,   // (384)
    const float* __restrict__ nW1,    // (128,128)
    const float* __restrict__ nb1,    // (128)
    const float* __restrict__ nW2,    // (128,128)
    const float* __restrict__ nb2,    // (128)
    const float* __restrict__ W_out,  // (128,128)
    const float* __restrict__ b_out,  // (128)
    const uint2* __restrict__ gi2,    // (T,B,NH) f16x4 (GI=1)
    float* __restrict__ out)          // (B,128)
{
    __shared__ __align__(16) _Float16 sh_h[2][NH];
    __shared__ __align__(16) _Float16 sh_tmp[NH];
    __shared__ __align__(16) _Float16 sh_ode[NH];
    __shared__ float sh_eo[NH];
    __shared__ float sh_dt[NT];
    __shared__ int   sh_m[NT];

    const int tid = threadIdx.x;
    const int j   = tid >> 2;   // output row 0..127
    const int q   = tid & 3;    // K-quarter
    const int b   = blockIdx.x;
    const int kb  = q * 32;     // f16 col base for H-dots
    const int qb  = q * 64;     // byte base within a 128-f16 row

    // bank rotation (verified 0 conflicts, r3/r5): chunk i -> byte qb + WSEL(i)*16
#define WSEL(i) (((i) + (q >> 1)) & 3)

    // ---- stage recurrent weights into f16x2 registers, pre-rotated ----
    uint w1[4][4], w2[4][4], whr[4][4], whz[4][4], whn[4][4];
#pragma unroll
    for (int i = 0; i < 4; ++i) {
        const int c = kb + (WSEL(i) << 3);
        ld8(nW1  + (j      )*NH + c, w1[i]);
        ld8(nW2  + (j      )*NH + c, w2[i]);
        ld8(W_hh + (j      )*NH + c, whr[i]);
        ld8(W_hh + (j + 128)*NH + c, whz[i]);
        ld8(W_hh + (j + 256)*NH + c, whn[i]);
    }
    uint wir[8], wiz[8], win[8];
    if constexpr (!GI) {
        const int kbi = q * 16;
        ld8(W_ih + (j      )*ND + kbi,     wir);
        ld8(W_ih + (j      )*ND + kbi + 8, wir + 4);
        ld8(W_ih + (j + 128)*ND + kbi,     wiz);
        ld8(W_ih + (j + 128)*ND + kbi + 8, wiz + 4);
        ld8(W_ih + (j + 256)*ND + kbi,     win);
        ld8(W_ih + (j + 256)*ND + kbi + 8, win + 4);
    }
    float bb1   = nb1[j];
    float bb2   = nb2[j];
    float brz_r = b_ih[j]       + b_hh[j];
    float brz_z = b_ih[j + 128] + b_hh[j + 128];
    float bin_n = b_ih[j + 256];
    float bhn_n = b_hh[j + 256];

#pragma unroll
    for (int i = 0; i < 4; ++i)
#pragma unroll
        for (int k = 0; k < 4; ++k) {
            PIN(w1[i][k]); PIN(w2[i][k]);
            PIN(whr[i][k]); PIN(whz[i][k]); PIN(whn[i][k]);
        }
    PIN(bb1); PIN(bb2); PIN(brz_r); PIN(brz_z); PIN(bin_n); PIN(bhn_n);

    // ---- stage dt / mask into LDS; init h ----
    for (int s = tid; s < NT; s += 512) {
        sh_dt[s] = (s == 0) ? 0.0f : (tps[s] - tps[s - 1]);
        sh_m[s]  = mask[b * NT + s];
    }
    if (tid < NH) sh_h[0][tid] = (_Float16)0.0f;
    __syncthreads();

    float hlast = 0.0f;
    int   seen  = 0;

    // 1-step-ahead prefetch state (raw barriers keep these loads in flight)
    const size_t gstride = (size_t)NB * NH;
    const uint2* gnext = gi2 + ((size_t)b * NH + j);
    const float* xbase = x + (size_t)b * NT * ND + q * 16;
    uint2  gc;
    float4 xc0, xc1, xc2, xc3;
    if constexpr (GI) {
        gc = *gnext;
        gnext += gstride;           // points at row for step 1
    } else {
        xc0 = *(const float4*)(xbase);
        xc1 = *(const float4*)(xbase + 4);
        xc2 = *(const float4*)(xbase + 8);
        xc3 = *(const float4*)(xbase + 12);
    }
    float dtc = sh_dt[0];
    int   mc  = sh_m[0];

    for (int s = 0; s < NT; ++s) {
        const int   cur = s & 1, nxt = cur ^ 1;
        const int   m   = mc;                    // uniform per block
        const float dte = seen ? dtc : 0.0f;     // r_fill freeze (uniform)

        // issue next-step prefetch (stays in flight across raw barriers)
        const int sn = (s + 1 < NT) ? (s + 1) : s;
        uint2  gn_;
        float4 xn0, xn1, xn2, xn3;
        if constexpr (GI) {
            gn_ = *gnext;
            if (s + 2 < NT) gnext += gstride;
        } else {
            const float* xr = xbase + (size_t)sn * ND;
            xn0 = *(const float4*)(xr);
            xn1 = *(const float4*)(xr + 4);
            xn2 = *(const float4*)(xr + 8);
            xn3 = *(const float4*)(xr + 12);
        }
        const float dt_n = sh_dt[sn];
        const int   m_n  = sh_m[sn];

        // input-gate contributions
        float grf, gzf, gnf;
        if constexpr (GI) {
            grf = f16lo(gc.x); gzf = f16hi(gc.x); gnf = f16lo(gc.y); // full dots
        } else {
            uint xh[8];
            xh[0] = pk(xc0.x, xc0.y); xh[1] = pk(xc0.z, xc0.w);
            xh[2] = pk(xc1.x, xc1.y); xh[3] = pk(xc1.z, xc1.w);
            xh[4] = pk(xc2.x, xc2.y); xh[5] = pk(xc2.z, xc2.w);
            xh[6] = pk(xc3.x, xc3.y); xh[7] = pk(xc3.z, xc3.w);
            grf = gzf = gnf = 0.0f;
#pragma unroll
            for (int k = 0; k < 8; ++k) {
                grf = fdot2u(wir[k], xh[k], grf);
                gzf = fdot2u(wiz[k], xh[k], gzf);
                gnf = fdot2u(win[k], xh[k], gnf);
            }
        }

        const float hj = (float)sh_h[cur][j];
        float hode_j;
        const _Float16* hsrc;

        if (dte != 0.0f) {
            // stage 1: tmp = tanh(W1 h + b1)
            float a1a = 0.0f, a1b = 0.0f;
#pragma unroll
            for (int i = 0; i < 4; ++i) {
                const uint4 hv = *(const uint4*)((const char*)&sh_h[cur][0] + qb + WSEL(i)*16);
                float& acc = (i & 1) ? a1b : a1a;
                acc = fdot2u(w1[i][0], hv.x, acc); acc = fdot2u(w1[i][1], hv.y, acc);
                acc = fdot2u(w1[i][2], hv.z, acc); acc = fdot2u(w1[i][3], hv.w, acc);
            }
            const float a1 = qsum(a1a + a1b);
            if (q == 0) sh_tmp[j] = (_Float16)tanh_f(a1 + bb1);
            WAVEBAR();

            // stage 2: h_ode = h + dt * (W2 tmp + b2)
            float a2a = 0.0f, a2b = 0.0f;
#pragma unroll
            for (int i = 0; i < 4; ++i) {
                const uint4 hv = *(const uint4*)((const char*)sh_tmp + qb + WSEL(i)*16);
                float& acc = (i & 1) ? a2b : a2a;
                acc = fdot2u(w2[i][0], hv.x, acc); acc = fdot2u(w2[i][1], hv.y, acc);
                acc = fdot2u(w2[i][2], hv.z, acc); acc = fdot2u(w2[i][3], hv.w, acc);
            }
            const float a2 = qsum(a2a + a2b);
            hode_j = hj + dte * (a2 + bb2);
            if (q == 0) sh_ode[j] = (_Float16)hode_j;
            WAVEBAR();
            hsrc = sh_ode;
        } else {
            hode_j = hj;
            hsrc = &sh_h[cur][0];
        }

        // stage 3: GRU recurrent dots (3 chains)
        float ar = 0.0f, az = 0.0f, an = 0.0f;
#pragma unroll
        for (int i = 0; i < 4; ++i) {
            const uint4 hv = *(const uint4*)((const char*)hsrc + qb + WSEL(i)*16);
            ar = fdot2u(whr[i][0], hv.x, ar); ar = fdot2u(whr[i][1], hv.y, ar);
            ar = fdot2u(whr[i][2], hv.z, ar); ar = fdot2u(whr[i][3], hv.w, ar);
            az = fdot2u(whz[i][0], hv.x, az); az = fdot2u(whz[i][1], hv.y, az);
            az = fdot2u(whz[i][2], hv.z, az); az = fdot2u(whz[i][3], hv.w, az);
            an = fdot2u(whn[i][0], hv.x, an); an = fdot2u(whn[i][1], hv.y, an);
            an = fdot2u(whn[i][2], hv.z, an); an = fdot2u(whn[i][3], hv.w, an);
        }
        float r, z, n;
        if constexpr (GI) {
            r = sigmoid_f(qsum(ar) + grf + brz_r);
            z = sigmoid_f(qsum(az) + gzf + brz_z);
            n = tanh_f(gnf + bin_n + r * (qsum(an) + bhn_n));
        } else {
            r = sigmoid_f(qsum(ar + grf) + brz_r);
            z = sigmoid_f(qsum(az + gzf) + brz_z);
            n = tanh_f(qsum(gnf) + bin_n + r * (qsum(an) + bhn_n));
        }
        const float hnew = m ? ((1.0f - z) * n + z * hode_j) : hode_j;

        if (q == 0) sh_h[nxt][j] = (_Float16)hnew;  // ping-pong write
        if (m) hlast = hnew;
        seen |= m;
        if constexpr (GI) { gc = gn_; }
        else { xc0 = xn0; xc1 = xn1; xc2 = xn2; xc3 = xn3; }
        dtc = dt_n; mc = m_n;
        WAVEBAR();
    }

    // epilogue (f32): out = W_out @ h_last + b_out
    if (q == 0) sh_eo[j] = hlast;
    __syncthreads();
    float ao = 0.0f;
#pragma unroll
    for (int i = 0; i < 8; ++i) {
        const int c = kb + (((i + 2 * q) & 7) << 2);
        const float4 wv = *(const float4*)(W_out + j*NH + c);
        const float4 hv = *(const float4*)(sh_eo + c);
        ao += wv.x*hv.x + wv.y*hv.y + wv.z*hv.z + wv.w*hv.w;
    }
    ao = qsum(ao);
    if (q == 0) out[b*NH + j] = ao + b_out[j];
}

extern "C" void kernel_launch(void* const* d_in, const int* in_sizes, int n_in,
                              void* d_out, int out_size, void* d_ws, size_t ws_size,
                              hipStream_t stream) {
    const float* x     = (const float*)d_in[0];
    const float* tps   = (const float*)d_in[1];
    const int*   mask  = (const int*)  d_in[2];
    const float* W_ih  = (const float*)d_in[3];
    const float* W_hh  = (const float*)d_in[4];
    const float* b_ih  = (const float*)d_in[5];
    const float* b_hh  = (const float*)d_in[6];
    const float* nW1   = (const float*)d_in[7];
    const float* nb1   = (const float*)d_in[8];
    const float* nW2   = (const float*)d_in[9];
    const float* nb2   = (const float*)d_in[10];
    const float* W_out = (const float*)d_in[11];
    const float* b_out = (const float*)d_in[12];
    float* out = (float*)d_out;

    const size_t ws_needed = (size_t)NT * NB * NH * sizeof(uint2); // 262,144,000
    if (ws_size >= ws_needed) {
        uint2* gi = (uint2*)d_ws;
        gi_pre<<<dim3(NB, 8), dim3(128), 0, stream>>>(x, W_ih, gi);
        gruode_scan<1><<<dim3(NB), dim3(512), 0, stream>>>(
            x, tps, mask, W_ih, W_hh, b_ih, b_hh,
            nW1, nb1, nW2, nb2, W_out, b_out, gi, out);
    } else {
        gruode_scan<0><<<dim3(NB), dim3(512), 0, stream>>>(
            x, tps, mask, W_ih, W_hh, b_ih, b_hh,
            nW1, nb1, nW2, nb2, W_out, b_out, nullptr, out);
    }
}

// Round 10
// 1163.257 us; speedup vs baseline: 1.3988x; 1.1642x over previous
//
#include <hip/hip_runtime.h>

#define NB 256
#define NT 1000
#define ND 64
#define NH 128

typedef _Float16 h2 __attribute__((ext_vector_type(2)));

static __device__ __forceinline__ uint pk(float a, float b) {
    return __builtin_bit_cast(uint, __builtin_amdgcn_cvt_pkrtz(a, b));
}
static __device__ __forceinline__ float fdot2u(uint a, uint b, float c) {
#if __has_builtin(__builtin_amdgcn_fdot2)
    return __builtin_amdgcn_fdot2(__builtin_bit_cast(h2, a),
                                  __builtin_bit_cast(h2, b), c, false);
#else
    h2 ha = __builtin_bit_cast(h2, a), hb = __builtin_bit_cast(h2, b);
    return c + (float)ha.x * (float)hb.x + (float)ha.y * (float)hb.y;
#endif
}
static __device__ __forceinline__ float sigmoid_f(float x) {
    float e = __builtin_amdgcn_exp2f(-1.4426950408889634f * x);
    return __builtin_amdgcn_rcpf(1.0f + e);
}
static __device__ __forceinline__ float tanh_f(float x) {
    float e = __builtin_amdgcn_exp2f(-2.8853900817779268f * x);
    return 2.0f * __builtin_amdgcn_rcpf(1.0f + e) - 1.0f;
}
// quad butterfly sum via DPP (lanes within each quad), ~4 instr, no LDS
static __device__ __forceinline__ float qsum(float v) {
    int a = __builtin_amdgcn_update_dpp(0, __builtin_bit_cast(int, v),
                                        0xB1, 0xF, 0xF, true); // quad_perm(1,0,3,2)
    v += __builtin_bit_cast(float, a);
    int b = __builtin_amdgcn_update_dpp(0, __builtin_bit_cast(int, v),
                                        0x4E, 0xF, 0xF, true); // quad_perm(2,3,0,1)
    v += __builtin_bit_cast(float, b);
    return v;
}
// load 8 consecutive f32, pack to 4 f16x2 regs
static __device__ __forceinline__ void ld8(const float* p, uint* d) {
    const float4 A = *(const float4*)p;
    const float4 B = *(const float4*)(p + 4);
    d[0] = pk(A.x, A.y); d[1] = pk(A.z, A.w);
    d[2] = pk(B.x, B.y); d[3] = pk(B.z, B.w);
}
#define PIN(v) asm volatile("" : "+v"(v))
// raw barrier: orders LDS only; global prefetch loads stay in flight
#define WAVEBAR() asm volatile("s_waitcnt lgkmcnt(0)\n\ts_barrier" ::: "memory")

// ---------- M = W_hh (384x128) @ nW2 (128x128), f32 ----------
__global__ __launch_bounds__(128) void mfuse(
    const float* __restrict__ W_hh, const float* __restrict__ nW2,
    float* __restrict__ M)
{
    __shared__ float wrow[NH];
    const int r = blockIdx.x;      // 0..383
    const int j = threadIdx.x;     // 0..127
    wrow[j] = W_hh[(size_t)r * NH + j];
    __syncthreads();
    float a0 = 0.0f, a1 = 0.0f, a2 = 0.0f, a3 = 0.0f;
#pragma unroll 8
    for (int k = 0; k < NH; k += 4) {
        a0 += wrow[k]     * nW2[(size_t)(k)     * NH + j];
        a1 += wrow[k + 1] * nW2[(size_t)(k + 1) * NH + j];
        a2 += wrow[k + 2] * nW2[(size_t)(k + 2) * NH + j];
        a3 += wrow[k + 3] * nW2[(size_t)(k + 3) * NH + j];
    }
    M[(size_t)r * NH + j] = (a0 + a1) + (a2 + a3);
}

// ---------- gi precompute: giu[t][b][row] (f16), row = g*128+j ----------
__global__ __launch_bounds__(384) void gi_pre(
    const float* __restrict__ x,      // (B,T,D)
    const float* __restrict__ W_ih,   // (384,64)
    ushort* __restrict__ giu)         // (T,B,384)
{
    __shared__ uint xt[125][32];      // f16-packed x tile (16 KB)
    const int tid = threadIdx.x;      // W_ih row
    const int b   = blockIdx.x;
    const int t0  = blockIdx.y * 125;

    uint wr[32];
    const float* wrow = W_ih + (size_t)tid * ND;
#pragma unroll
    for (int k = 0; k < 8; ++k) ld8(wrow + k * 8, wr + k * 4);

    for (int i = tid; i < 125 * 32; i += 384) {
        const int t = i >> 5, c = i & 31;
        const float2 v = *(const float2*)(x + ((size_t)b * NT + t0 + t) * ND + c * 2);
        xt[t][c] = pk(v.x, v.y);
    }
    __syncthreads();

    for (int t = 0; t < 125; ++t) {
        const uint4* xr = (const uint4*)&xt[t][0];   // broadcast reads
        float a0 = 0.0f, a1 = 0.0f;
#pragma unroll
        for (int k4 = 0; k4 < 8; ++k4) {
            const uint4 hv = xr[k4];
            a0 = fdot2u(wr[k4 * 4 + 0], hv.x, a0);
            a1 = fdot2u(wr[k4 * 4 + 1], hv.y, a1);
            a0 = fdot2u(wr[k4 * 4 + 2], hv.z, a0);
            a1 = fdot2u(wr[k4 * 4 + 3], hv.w, a1);
        }
        giu[((size_t)(t0 + t) * NB + b) * 384 + tid] =
            __builtin_bit_cast(ushort, (_Float16)(a0 + a1));
    }
}

// ---------- fused 2-phase scan ----------
template<int GI>
__global__
__attribute__((amdgpu_flat_work_group_size(512, 512)))
__attribute__((amdgpu_waves_per_eu(2, 2)))
void gruode_scan(
    const float* __restrict__ x,      // (B,T,D)  (GI=0 only)
    const float* __restrict__ tps,    // (T)
    const int*   __restrict__ mask,   // (B,T)
    const float* __restrict__ W_ih,   // (384,64)  (GI=0 only)
    const float* __restrict__ W_hh,   // (384,128)
    const float* __restrict__ b_ih,   // (384)
    const float* __restrict__ b_hh,   // (384)
    const float* __restrict__ nW1,    // (128,128)
    const float* __restrict__ nb1,    // (128)
    const float* __restrict__ nW2,    // (128,128)
    const float* __restrict__ nb2,    // (128)
    const float* __restrict__ W_out,  // (128,128)
    const float* __restrict__ b_out,  // (128)
    const float* __restrict__ Mw,     // (384,128) = W_hh @ nW2
    const ushort* __restrict__ giu,   // (T,B,384) f16 (GI=1)
    float* __restrict__ out)          // (B,128)
{
    __shared__ __align__(16) _Float16 sh_h[2][NH];
    __shared__ __align__(16) _Float16 sh_tmp[NH];
    __shared__ float sh_eo[NH];
    __shared__ float sh_dt[NT];
    __shared__ int   sh_m[NT];

    const int tid = threadIdx.x;
    const int j   = tid >> 2;   // output row 0..127
    const int q   = tid & 3;    // K-quarter
    const int b   = blockIdx.x;
    const int kb  = q * 32;     // f16 col base
    const int qb  = q * 64;     // byte base within 128-f16 row

#define WSEL(i) (((i) + (q >> 1)) & 3)   // verified conflict-free rotation

    // ---- stage weights (8 fragment sets = 128 u32) ----
    uint w1[4][4], w2[4][4], whr[4][4], whz[4][4], whn[4][4];
    uint mr[4][4], mz[4][4], mn[4][4];
#pragma unroll
    for (int i = 0; i < 4; ++i) {
        const int c = kb + (WSEL(i) << 3);
        ld8(nW1  + (size_t)(j      ) * NH + c, w1[i]);
        ld8(nW2  + (size_t)(j      ) * NH + c, w2[i]);
        ld8(W_hh + (size_t)(j      ) * NH + c, whr[i]);
        ld8(W_hh + (size_t)(j + 128) * NH + c, whz[i]);
        ld8(W_hh + (size_t)(j + 256) * NH + c, whn[i]);
        ld8(Mw   + (size_t)(j      ) * NH + c, mr[i]);
        ld8(Mw   + (size_t)(j + 128) * NH + c, mz[i]);
        ld8(Mw   + (size_t)(j + 256) * NH + c, mn[i]);
    }
    uint wir[8], wiz[8], win[8];
    if constexpr (!GI) {
        const int kbi = q * 16;
        ld8(W_ih + (size_t)(j      ) * ND + kbi,     wir);
        ld8(W_ih + (size_t)(j      ) * ND + kbi + 8, wir + 4);
        ld8(W_ih + (size_t)(j + 128) * ND + kbi,     wiz);
        ld8(W_ih + (size_t)(j + 128) * ND + kbi + 8, wiz + 4);
        ld8(W_ih + (size_t)(j + 256) * ND + kbi,     win);
        ld8(W_ih + (size_t)(j + 256) * ND + kbi + 8, win + 4);
    }
    float bb1   = nb1[j];
    float bb2   = nb2[j];
    float brz_r = b_ih[j]       + b_hh[j];
    float brz_z = b_ih[j + 128] + b_hh[j + 128];
    float bin_n = b_ih[j + 256];
    float bhn_n = b_hh[j + 256];

    // ---- cvec = W_hh @ node_b2 (per own j), from resident fragments ----
    float cr = 0.0f, cz = 0.0f, cn = 0.0f;
    {
        uint b2p[4];
#pragma unroll
        for (int i = 0; i < 4; ++i) {
            const int c = kb + (WSEL(i) << 3);
            ld8(nb2 + c, b2p);
#pragma unroll
            for (int k = 0; k < 4; ++k) {
                cr = fdot2u(whr[i][k], b2p[k], cr);
                cz = fdot2u(whz[i][k], b2p[k], cz);
                cn = fdot2u(whn[i][k], b2p[k], cn);
            }
        }
        cr = qsum(cr); cz = qsum(cz); cn = qsum(cn);
    }

#pragma unroll
    for (int i = 0; i < 4; ++i)
#pragma unroll
        for (int k = 0; k < 4; ++k) {
            PIN(w1[i][k]); PIN(w2[i][k]);
            PIN(whr[i][k]); PIN(whz[i][k]); PIN(whn[i][k]);
            PIN(mr[i][k]); PIN(mz[i][k]); PIN(mn[i][k]);
        }
    PIN(bb1); PIN(bb2); PIN(brz_r); PIN(brz_z); PIN(bin_n); PIN(bhn_n);
    PIN(cr); PIN(cz); PIN(cn);

    // ---- stage dt / mask; init h ----
    for (int s = tid; s < NT; s += 512) {
        sh_dt[s] = (s == 0) ? 0.0f : (tps[s] - tps[s - 1]);
        sh_m[s]  = mask[b * NT + s];
    }
    if (tid < NH) sh_h[0][tid] = (_Float16)0.0f;
    __syncthreads();

    float hj = 0.0f, hlast = 0.0f;
    int   seen = 0;

    // gi prefetch, 2 steps deep
    const size_t GSTR = (size_t)NB * 384;
    const ushort* gb = giu + (size_t)b * 384 + j;
    ushort c_r, c_z, c_n, n_r, n_z, n_n;
    const float* xbase = x + (size_t)b * NT * ND + q * 16;
    float4 xc0, xc1, xc2, xc3;
    if constexpr (GI) {
        c_r = gb[0];           c_z = gb[128];           c_n = gb[256];
        n_r = gb[GSTR];        n_z = gb[GSTR + 128];    n_n = gb[GSTR + 256];
    } else {
        xc0 = *(const float4*)(xbase);
        xc1 = *(const float4*)(xbase + 4);
        xc2 = *(const float4*)(xbase + 8);
        xc3 = *(const float4*)(xbase + 12);
    }
    float dtc = sh_dt[0];
    int   mc  = sh_m[0];

    for (int s = 0; s < NT; ++s) {
        const int cur = s & 1, nxt = cur ^ 1;

        // issue prefetches (stay in flight across raw barriers)
        ushort p_r, p_z, p_n;
        float4 xn0, xn1, xn2, xn3;
        if constexpr (GI) {
            const int sp = (s + 2 < NT) ? (s + 2) : (NT - 1);
            const ushort* g2 = gb + (size_t)sp * GSTR;
            p_r = g2[0]; p_z = g2[128]; p_n = g2[256];
        } else {
            const int sn_ = (s + 1 < NT) ? (s + 1) : s;
            const float* xr = xbase + (size_t)sn_ * ND;
            xn0 = *(const float4*)(xr);
            xn1 = *(const float4*)(xr + 4);
            xn2 = *(const float4*)(xr + 8);
            xn3 = *(const float4*)(xr + 12);
        }
        const int sn = (s + 1 < NT) ? (s + 1) : s;
        const float dt_n = sh_dt[sn];
        const int   m_n  = sh_m[sn];

        const int   m   = mc;                  // uniform per block
        const float dte = seen ? dtc : 0.0f;   // r_fill freeze

        // input-gate contributions
        float grf, gzf, gnf;
        if constexpr (GI) {
            grf = (float)__builtin_bit_cast(_Float16, c_r);
            gzf = (float)__builtin_bit_cast(_Float16, c_z);
            gnf = (float)__builtin_bit_cast(_Float16, c_n);
        } else {
            uint xh[8];
            xh[0] = pk(xc0.x, xc0.y); xh[1] = pk(xc0.z, xc0.w);
            xh[2] = pk(xc1.x, xc1.y); xh[3] = pk(xc1.z, xc1.w);
            xh[4] = pk(xc2.x, xc2.y); xh[5] = pk(xc2.z, xc2.w);
            xh[6] = pk(xc3.x, xc3.y); xh[7] = pk(xc3.z, xc3.w);
            grf = gzf = gnf = 0.0f;
#pragma unroll
            for (int k = 0; k < 8; ++k) {
                grf = fdot2u(wir[k], xh[k], grf);
                gzf = fdot2u(wiz[k], xh[k], gzf);
                gnf = fdot2u(win[k], xh[k], gnf);
            }
        }

        // ---- phase A: a1 = W1 h ; AH = W_hh h (same LDS reads) ----
        float a1 = 0.0f, ahr = 0.0f, ahz = 0.0f, ahn = 0.0f;
        const char* hb = (const char*)&sh_h[cur][0];
#pragma unroll
        for (int i = 0; i < 4; ++i) {
            const uint4 hv = *(const uint4*)(hb + qb + WSEL(i) * 16);
            a1  = fdot2u(w1[i][0],  hv.x, a1);  a1  = fdot2u(w1[i][1],  hv.y, a1);
            a1  = fdot2u(w1[i][2],  hv.z, a1);  a1  = fdot2u(w1[i][3],  hv.w, a1);
            ahr = fdot2u(whr[i][0], hv.x, ahr); ahr = fdot2u(whr[i][1], hv.y, ahr);
            ahr = fdot2u(whr[i][2], hv.z, ahr); ahr = fdot2u(whr[i][3], hv.w, ahr);
            ahz = fdot2u(whz[i][0], hv.x, ahz); ahz = fdot2u(whz[i][1], hv.y, ahz);
            ahz = fdot2u(whz[i][2], hv.z, ahz); ahz = fdot2u(whz[i][3], hv.w, ahz);
            ahn = fdot2u(whn[i][0], hv.x, ahn); ahn = fdot2u(whn[i][1], hv.y, ahn);
            ahn = fdot2u(whn[i][2], hv.z, ahn); ahn = fdot2u(whn[i][3], hv.w, ahn);
        }
        const float a1q = qsum(a1);
        if (q == 0) sh_tmp[j] = (_Float16)tanh_f(a1q + bb1);
        WAVEBAR();

        // ---- phase B: a2 = W2 tmp ; AM = M tmp ; gates ----
        float a2 = 0.0f, amr = 0.0f, amz = 0.0f, amn = 0.0f;
#pragma unroll
        for (int i = 0; i < 4; ++i) {
            const uint4 tv = *(const uint4*)((const char*)sh_tmp + qb + WSEL(i) * 16);
            a2  = fdot2u(w2[i][0], tv.x, a2);  a2  = fdot2u(w2[i][1], tv.y, a2);
            a2  = fdot2u(w2[i][2], tv.z, a2);  a2  = fdot2u(w2[i][3], tv.w, a2);
            amr = fdot2u(mr[i][0], tv.x, amr); amr = fdot2u(mr[i][1], tv.y, amr);
            amr = fdot2u(mr[i][2], tv.z, amr); amr = fdot2u(mr[i][3], tv.w, amr);
            amz = fdot2u(mz[i][0], tv.x, amz); amz = fdot2u(mz[i][1], tv.y, amz);
            amz = fdot2u(mz[i][2], tv.z, amz); amz = fdot2u(mz[i][3], tv.w, amz);
            amn = fdot2u(mn[i][0], tv.x, amn); amn = fdot2u(mn[i][1], tv.y, amn);
            amn = fdot2u(mn[i][2], tv.z, amn); amn = fdot2u(mn[i][3], tv.w, amn);
        }
        const float a2q  = qsum(a2);
        const float hode = hj + dte * (a2q + bb2);
        const float sr_t = qsum(ahr + dte * amr) + dte * cr;  // (W_hh_r h_ode)[j]
        const float sz_t = qsum(ahz + dte * amz) + dte * cz;
        const float hn_t = qsum(ahn + dte * amn) + dte * cn;

        const float r = sigmoid_f(sr_t + grf + brz_r);
        const float z = sigmoid_f(sz_t + gzf + brz_z);
        const float n = tanh_f(gnf + bin_n + r * (hn_t + bhn_n));
        const float hnew = m ? ((1.0f - z) * n + z * hode) : hode;

        if (q == 0) sh_h[nxt][j] = (_Float16)hnew;
        hj = hnew;
        if (m) hlast = hnew;
        seen |= m;
        if constexpr (GI) { c_r = n_r; c_z = n_z; c_n = n_n; n_r = p_r; n_z = p_z; n_n = p_n; }
        else { xc0 = xn0; xc1 = xn1; xc2 = xn2; xc3 = xn3; }
        dtc = dt_n; mc = m_n;
        WAVEBAR();
    }

    // ---- epilogue (f32): out = W_out @ h_last + b_out ----
    if (q == 0) sh_eo[j] = hlast;
    __syncthreads();
    float ao = 0.0f;
#pragma unroll
    for (int i = 0; i < 8; ++i) {
        const int c = kb + (((i + 2 * q) & 7) << 2);
        const float4 wv = *(const float4*)(W_out + (size_t)j * NH + c);
        const float4 hv = *(const float4*)(sh_eo + c);
        ao += wv.x * hv.x + wv.y * hv.y + wv.z * hv.z + wv.w * hv.w;
    }
    ao = qsum(ao);
    if (q == 0) out[(size_t)b * NH + j] = ao + b_out[j];
}

extern "C" void kernel_launch(void* const* d_in, const int* in_sizes, int n_in,
                              void* d_out, int out_size, void* d_ws, size_t ws_size,
                              hipStream_t stream) {
    const float* x     = (const float*)d_in[0];
    const float* tps   = (const float*)d_in[1];
    const int*   mask  = (const int*)  d_in[2];
    const float* W_ih  = (const float*)d_in[3];
    const float* W_hh  = (const float*)d_in[4];
    const float* b_ih  = (const float*)d_in[5];
    const float* b_hh  = (const float*)d_in[6];
    const float* nW1   = (const float*)d_in[7];
    const float* nb1   = (const float*)d_in[8];
    const float* nW2   = (const float*)d_in[9];
    const float* nb2   = (const float*)d_in[10];
    const float* W_out = (const float*)d_in[11];
    const float* b_out = (const float*)d_in[12];
    float* out = (float*)d_out;

    const size_t M_BYTES  = (size_t)384 * NH * sizeof(float);          // 196,608
    const size_t GI_BYTES = (size_t)NT * NB * 384 * sizeof(ushort);    // 196,608,000
    float*  Mw  = (float*)d_ws;
    ushort* giu = (ushort*)((char*)d_ws + M_BYTES);

    mfuse<<<dim3(384), dim3(128), 0, stream>>>(W_hh, nW2, Mw);
    if (ws_size >= M_BYTES + GI_BYTES) {
        gi_pre<<<dim3(NB, 8), dim3(384), 0, stream>>>(x, W_ih, giu);
        gruode_scan<1><<<dim3(NB), dim3(512), 0, stream>>>(
            x, tps, mask, W_ih, W_hh, b_ih, b_hh,
            nW1, nb1, nW2, nb2, W_out, b_out, Mw, giu, out);
    } else {
        gruode_scan<0><<<dim3(NB), dim3(512), 0, stream>>>(
            x, tps, mask, W_ih, W_hh, b_ih, b_hh,
            nW1, nb1, nW2, nb2, W_out, b_out, Mw, nullptr, out);
    }
}